// Round 9
// baseline (868.228 us; speedup 1.0000x reference)
//
#include <hip/hip_runtime.h>
#include <math.h>

#define T_ 1024
#define D_ 3
#define H_ 64

typedef _Float16 f16x8 __attribute__((ext_vector_type(8)));
typedef float f32x4 __attribute__((ext_vector_type(4)));

__device__ __forceinline__ float sigmoid_f(float x) {
    return __builtin_amdgcn_rcpf(1.0f + __expf(-x));
}

#define MFMA(A, B, C) __builtin_amdgcn_mfma_f32_16x16x32_f16((A), (B), (C), 0, 0, 0)
// lgkm-only barrier: only LDS data crosses wave boundaries at step barriers.
#define LDS_BARRIER() asm volatile("s_waitcnt lgkmcnt(0)\ns_barrier" ::: "memory")

// Dual-phase Siamese: 4 waves/block, 16 seqs/block, both chains per wave,
// staggered by half a step so every barrier shadow is filled with the OTHER
// chain's work (LDS fragment reads, h-publish, x-MFMAs). Per iteration:
//   computeA -> barrier -> {readB, publishA(t+1), xprepA(t+1)} ->
//   computeB -> barrier -> {readA, publishB(t+1), xprepB(t+1)}
// Fragments are pre-read in the prior shadow, so each post-barrier chain
// starts on registers. Single h-buffer per chain (publish/read are always
// barrier-separated). Round-6 failed ONLY because both chains shared one
// phase; this staggering is the fix. exp2-folded weights as round 5.
__global__ __launch_bounds__(256, 1) void gru_dualphase(
    const float* __restrict__ x1, const float* __restrict__ x2,
    const float* __restrict__ W_ih, const float* __restrict__ W_hh,
    const float* __restrict__ b_ih, const float* __restrict__ b_hh,
    const float* __restrict__ W1, const float* __restrict__ b1,
    const float* __restrict__ W2, const float* __restrict__ b2,
    float* __restrict__ out)
{
    const int lane = threadIdx.x & 63;
    const int w    = threadIdx.x >> 6;   // wave 0..3: owns units 16w..16w+15
    const int c    = lane & 15;          // A-m / C-D col / B-n
    const int q    = lane >> 4;          // quad
    const int u    = 16 * w + c;         // this lane's hidden-unit column
    const int seq0 = blockIdx.x * 16;

    const float SRZ = -1.44269504f;      // -log2(e): r,z rows (exp2(-x) form)
    const float SN  =  2.88539008f;      // 2*log2(e): n rows (exp2(2x) form)
    const float gsc[3] = {SRZ, SRZ, SN};

    // ---- h-part B-fragments (scaled) ----
    f16x8 wf[3][2];
    #pragma unroll
    for (int g = 0; g < 3; ++g)
        #pragma unroll
        for (int ks = 0; ks < 2; ++ks) {
            const float* p = W_hh + (size_t)(g * 64 + u) * H_ + 32 * ks + q * 8;
            f16x8 v;
            #pragma unroll
            for (int j = 0; j < 8; ++j) v[j] = (_Float16)(p[j] * gsc[g]);
            wf[g][ks] = v;
        }

    // ---- x-part B-fragments (scaled; nonzero only in q==0 lanes, j<3) ----
    f16x8 bxf[3];
    #pragma unroll
    for (int g = 0; g < 3; ++g) {
        f16x8 v = {};
        if (q == 0) {
            #pragma unroll
            for (int d = 0; d < 3; ++d)
                v[d] = (_Float16)(W_ih[(size_t)(g * 64 + u) * D_ + d] * gsc[g]);
        }
        bxf[g] = v;
    }

    // ---- bias C-splats (scaled) ----
    const float comb_r = (b_ih[u]      + b_hh[u])      * SRZ;
    const float comb_z = (b_ih[64 + u] + b_hh[64 + u]) * SRZ;
    const float bxn    = b_ih[128 + u] * SN;
    const float bhn    = b_hh[128 + u] * SN;
    const f32x4 Cr  = {comb_r, comb_r, comb_r, comb_r};
    const f32x4 Cz  = {comb_z, comb_z, comb_z, comb_z};
    const f32x4 Cxn = {bxn, bxn, bxn, bxn};
    const f32x4 Chn = {bhn, bhn, bhn, bhn};

    // ---- x pointers: A-frag row c = seq seq0+c; chain A = x1, B = x2 ----
    const float4* xpA = (const float4*)(x1 + (size_t)(seq0 + c) * (T_ * D_));
    const float4* xpB = (const float4*)(x2 + (size_t)(seq0 + c) * (T_ * D_));

    // single h-buffer per chain: [row][unit], stride 72 halves
    __shared__ alignas(16) _Float16 hbA[16 * 72];
    __shared__ alignas(16) _Float16 hbB[16 * 72];
    __shared__ float dlds[16][68];

    float hA[4], hB[4];
    #pragma unroll
    for (int r = 0; r < 4; ++r) { hA[r] = 0.f; hB[r] = 0.f; }

    f32x4 arA, azA, axnA;   // step-t preacts carried (x-part + biases, then h-part)
    f32x4 arB, azB, axnB;
    f16x8 fa0, fa1;         // chain-A fragments for step t (pre-read in shadow)

    auto xprep = [&](float x0, float x1v, float x2v,
                     f32x4& ar, f32x4& az, f32x4& axn) {
        f16x8 ax = {};
        ax[0] = (_Float16)x0; ax[1] = (_Float16)x1v; ax[2] = (_Float16)x2v;
        ar  = MFMA(ax, bxf[0], Cr);
        az  = MFMA(ax, bxf[1], Cz);
        axn = MFMA(ax, bxf[2], Cxn);
    };

    auto gates = [&](const f32x4& ar, const f32x4& az, const f32x4& axn,
                     const f32x4& ahn, float (&h)[4]) {
        #pragma unroll
        for (int r = 0; r < 4; ++r) {
            const float eu = __builtin_amdgcn_exp2f(ar[r]);   // e^{-pre_r}
            const float ev = __builtin_amdgcn_exp2f(az[r]);   // e^{-pre_z}
            const float pu = 1.0f + eu, pv = 1.0f + ev;
            const float inv = __builtin_amdgcn_rcpf(pu * pv);
            const float rr = pv * inv;                        // sigmoid(pre_r)
            const float zz = pu * inv;                        // sigmoid(pre_z)
            const float tt = axn[r] + rr * ahn[r];            // 2log2e * pre_n
            const float e2 = __builtin_amdgcn_exp2f(tt);
            const float nn = 1.0f - 2.0f * __builtin_amdgcn_rcpf(e2 + 1.0f);
            h[r] = nn + zz * (h[r] - nn);
        }
    };

    // x batches: 3 float4 = 4 steps per chain
    float4 xcA[3], xcB[3];
    #pragma unroll
    for (int i = 0; i < 3; ++i) { xcA[i] = xpA[i]; xcB[i] = xpB[i]; }

    // ---- prologue: establish iteration invariant for t=0 ----
    #pragma unroll
    for (int r = 0; r < 4; ++r) {
        hbA[(4 * q + r) * 72 + u] = (_Float16)0.f;
        hbB[(4 * q + r) * 72 + u] = (_Float16)0.f;
    }
    xprep(xcA[0].x, xcA[0].y, xcA[0].z, arA, azA, axnA);
    xprep(xcB[0].x, xcB[0].y, xcB[0].z, arB, azB, axnB);
    LDS_BARRIER();
    fa0 = *(const f16x8*)&hbA[c * 72 + q * 8];
    fa1 = *(const f16x8*)&hbA[c * 72 + 32 + q * 8];

    // one iteration: advance BOTH chains by one step; x* = x(t+1) slots
    auto iter = [&](float a0x, float a1x, float a2x,
                    float b0x, float b1x, float b2x) {
        // -- chain A compute (step t): fragments already in regs --
        arA = MFMA(fa0, wf[0][0], arA);
        azA = MFMA(fa0, wf[1][0], azA);
        f32x4 ahnA = MFMA(fa0, wf[2][0], Chn);
        arA = MFMA(fa1, wf[0][1], arA);
        azA = MFMA(fa1, wf[1][1], azA);
        ahnA = MFMA(fa1, wf[2][1], ahnA);
        gates(arA, azA, axnA, ahnA, hA);
        LDS_BARRIER();                                    // fences hbB(t)
        // shadow: read B-frags, publish A(t+1), xprep A(t+1)
        const f16x8 fb0 = *(const f16x8*)&hbB[c * 72 + q * 8];
        const f16x8 fb1 = *(const f16x8*)&hbB[c * 72 + 32 + q * 8];
        #pragma unroll
        for (int r = 0; r < 4; ++r)
            hbA[(4 * q + r) * 72 + u] = (_Float16)hA[r];
        xprep(a0x, a1x, a2x, arA, azA, axnA);
        // -- chain B compute (step t) --
        arB = MFMA(fb0, wf[0][0], arB);
        azB = MFMA(fb0, wf[1][0], azB);
        f32x4 ahnB = MFMA(fb0, wf[2][0], Chn);
        arB = MFMA(fb1, wf[0][1], arB);
        azB = MFMA(fb1, wf[1][1], azB);
        ahnB = MFMA(fb1, wf[2][1], ahnB);
        gates(arB, azB, axnB, ahnB, hB);
        LDS_BARRIER();                                    // fences hbA(t+1)
        // shadow: read A-frags (t+1), publish B(t+1), xprep B(t+1)
        fa0 = *(const f16x8*)&hbA[c * 72 + q * 8];
        fa1 = *(const f16x8*)&hbA[c * 72 + 32 + q * 8];
        #pragma unroll
        for (int r = 0; r < 4; ++r)
            hbB[(4 * q + r) * 72 + u] = (_Float16)hB[r];
        xprep(b0x, b1x, b2x, arB, azB, axnB);
    };

    for (int t0 = 0; t0 < T_; t0 += 4) {
        float4 xnA[3], xnB[3];
        const int tb = (t0 + 4 < T_) ? (3 * (t0 + 4)) / 4 : (3 * t0) / 4;
        #pragma unroll
        for (int i = 0; i < 3; ++i) { xnA[i] = xpA[tb + i]; xnB[i] = xpB[tb + i]; }
        // iteration t0+i consumes x(t0+i+1) = flat slots 3(i+1)..3(i+1)+2
        iter(xcA[0].w, xcA[1].x, xcA[1].y, xcB[0].w, xcB[1].x, xcB[1].y);
        iter(xcA[1].z, xcA[1].w, xcA[2].x, xcB[1].z, xcB[1].w, xcB[2].x);
        iter(xcA[2].y, xcA[2].z, xcA[2].w, xcB[2].y, xcB[2].z, xcB[2].w);
        iter(xnA[0].x, xnA[0].y, xnA[0].z, xnB[0].x, xnB[0].y, xnB[0].z);
        #pragma unroll
        for (int i = 0; i < 3; ++i) { xcA[i] = xnA[i]; xcB[i] = xnB[i]; }
    }

    // ---- epilogue: |hA-hB| (register diff) -> MLP for 16 seqs ----
    #pragma unroll
    for (int r = 0; r < 4; ++r)
        dlds[4 * q + r][u] = fabsf(hA[r] - hB[r]);
    __syncthreads();
    if (w < 2) {
        const int s = 8 * w + (lane >> 3);   // seq within block 0..15
        const int b = lane & 7;              // hidden-row group base
        float am[4];
        #pragma unroll
        for (int i = 0; i < 4; ++i) am[i] = b1[b + 8 * i];
        #pragma unroll
        for (int k4 = 0; k4 < 16; ++k4) {
            const float4 dvec = *(const float4*)&dlds[s][k4 * 4];
            #pragma unroll
            for (int i = 0; i < 4; ++i) {
                const float4 wv = *(const float4*)&W1[(b + 8 * i) * H_ + k4 * 4];
                am[i] += dvec.x * wv.x + dvec.y * wv.y + dvec.z * wv.z + dvec.w * wv.w;
            }
        }
        float part = 0.f;
        #pragma unroll
        for (int i = 0; i < 4; ++i) part += fmaxf(am[i], 0.f) * W2[b + 8 * i];
        part += __shfl_xor(part, 1);
        part += __shfl_xor(part, 2);
        part += __shfl_xor(part, 4);
        if (b == 0) out[seq0 + s] = sigmoid_f(part + b2[0]);
    }
}

extern "C" void kernel_launch(void* const* d_in, const int* in_sizes, int n_in,
                              void* d_out, int out_size, void* d_ws, size_t ws_size,
                              hipStream_t stream) {
    const float* x1   = (const float*)d_in[0];
    const float* x2   = (const float*)d_in[1];
    const float* W_ih = (const float*)d_in[2];
    const float* W_hh = (const float*)d_in[3];
    const float* b_ih = (const float*)d_in[4];
    const float* b_hh = (const float*)d_in[5];
    const float* W1   = (const float*)d_in[6];
    const float* b1   = (const float*)d_in[7];
    const float* W2   = (const float*)d_in[8];
    const float* b2   = (const float*)d_in[9];

    const int B = in_sizes[0] / (T_ * D_);      // 4096
    dim3 grid(B / 16), block(256);
    gru_dualphase<<<grid, block, 0, stream>>>(x1, x2, W_ih, W_hh, b_ih, b_hh,
                                              W1, b1, W2, b2, (float*)d_out);
}